// Round 1
// 786.921 us; speedup vs baseline: 1.0169x; 1.0169x over previous
//
#include <hip/hip_runtime.h>
#include <hip/hip_bf16.h>
#include <stdint.h>

typedef __attribute__((ext_vector_type(4))) float f32x4;
typedef __attribute__((ext_vector_type(8))) short bf16x8;

#define N_GENE 16384
#define N_TF   512
#define DMODEL 512
#define L2E    1.44269504088896340736f

__device__ __forceinline__ float bf2f(unsigned short u) {
    union { unsigned int i; float f; } v; v.i = ((unsigned int)u) << 16; return v.f;
}
// single-instruction RNE f32->bf16 (v_cvt_pk with duplicated operand; result in low 16)
__device__ __forceinline__ unsigned short f2bf(float f) {
    unsigned int r;
    asm("v_cvt_pk_bf16_f32 %0, %1, %1" : "=v"(r) : "v"(f));
    return (unsigned short)r;
}
__device__ __forceinline__ float fast_rcp(float x) {
    float r; asm("v_rcp_f32 %0, %1" : "=v"(r) : "v"(x)); return r;
}
__device__ __forceinline__ float fast_exp2(float x) {
    float r; asm("v_exp_f32 %0, %1" : "=v"(r) : "v"(x)); return r;
}

#define GLOBAL_AS(p) ((const __attribute__((address_space(1))) void*)(p))
#define LDS_AS(p)    ((__attribute__((address_space(3))) void*)(p))

// ---------------------------------------------------------------- utilities
__global__ void zerof(float* __restrict__ p, int n) {
    int i = blockIdx.x * blockDim.x + threadIdx.x;
    if (i < n) p[i] = 0.f;
}

__global__ void copy16(const int4* __restrict__ src, int4* __restrict__ dst, int n) {
    int i = blockIdx.x * blockDim.x + threadIdx.x;
    if (i < n) dst[i] = src[i];
}

// fp32 -> bf16 convert, 3 matrices of [16384][512], 8 elems/thread
__global__ __launch_bounds__(256) void cvt3(const float* __restrict__ z0, const float* __restrict__ z1,
                                            const float* __restrict__ z2, unsigned short* __restrict__ dst) {
    const float* s = blockIdx.z == 0 ? z0 : (blockIdx.z == 1 ? z1 : z2);
    size_t i = ((size_t)blockIdx.x * 256 + threadIdx.x) * 8;
    float4 a = *(const float4*)(s + i);
    float4 b = *(const float4*)(s + i + 4);
    unsigned int w0, w1, w2, w3;
    asm("v_cvt_pk_bf16_f32 %0, %1, %2" : "=v"(w0) : "v"(a.x), "v"(a.y));
    asm("v_cvt_pk_bf16_f32 %0, %1, %2" : "=v"(w1) : "v"(a.z), "v"(a.w));
    asm("v_cvt_pk_bf16_f32 %0, %1, %2" : "=v"(w2) : "v"(b.x), "v"(b.y));
    asm("v_cvt_pk_bf16_f32 %0, %1, %2" : "=v"(w3) : "v"(b.z), "v"(b.w));
    uint4 o; o.x = w0; o.y = w1; o.z = w2; o.w = w3;
    *(uint4*)(dst + (size_t)blockIdx.z * (size_t)N_GENE * 512 + i) = o;
}

// transpose+convert 6 [512x512] fp32 weight matrices -> bf16: dst[m][n*512+k] = src[m][k*512+n]
__global__ void transpose6(const float* __restrict__ s0, const float* __restrict__ s1,
                           const float* __restrict__ s2, const float* __restrict__ s3,
                           const float* __restrict__ s4, const float* __restrict__ s5,
                           unsigned short* __restrict__ dst) {
    const float* srcs[6] = { s0, s1, s2, s3, s4, s5 };
    int m = blockIdx.z;
    __shared__ unsigned short tile[32][33];
    int x = blockIdx.x * 32 + threadIdx.x;       // source col (n)
    int y0 = blockIdx.y * 32;                    // source row base (k)
    const float* src = srcs[m];
    for (int i = threadIdx.y; i < 32; i += 8)
        tile[i][threadIdx.x] = f2bf(src[(size_t)(y0 + i) * 512 + x]);
    __syncthreads();
    int xo = blockIdx.y * 32 + threadIdx.x;      // dest col (= k)
    int yo0 = blockIdx.x * 32;                   // dest row base (= n)
    unsigned short* d = dst + (size_t)m * 512 * 512;
    for (int i = threadIdx.y; i < 32; i += 8)
        d[(size_t)(yo0 + i) * 512 + xo] = tile[threadIdx.x][i];
}

// ---------------------------------------------------------------- GEMM C[M,512] = A[M,512] @ Bt^T
// A bf16 row-major (optional row gather via idx), Bt bf16 row-major [n][k], C bf16.
// Tile 128x128, BK=64, 4 waves (2x2), mfma 16x16x32.
// Staging: global_load_lds width=16, linear LDS dest, source pre-swizzled so that
// ds_read with byte^=((row&7)<<4) is bank-conflict-free (G4 + rule-21 both-sides swizzle).
__global__ __launch_bounds__(256) void gemm_bf16(const unsigned short* __restrict__ A,
                                                 const unsigned short* __restrict__ Bt,
                                                 unsigned short* __restrict__ C,
                                                 const int* __restrict__ idx) {
    __shared__ unsigned short As[128 * 64];   // 16 KB
    __shared__ unsigned short Bs[128 * 64];   // 16 KB
    const int tid = threadIdx.x;
    const int lane = tid & 63;
    const int w = tid >> 6;
    const int mBase = blockIdx.y * 128;
    const int nBase = blockIdx.x * 128;
    const int wm = (w & 1) * 64;
    const int wn = (w >> 1) * 64;
    const int lm = lane & 15, lq = lane >> 4;

    // staging geometry: chunk c = i*256 + tid covers row c>>3, 16B-segment c&7
    const int rbase = tid >> 3;                       // 0..31
    const int seg = tid & 7;
    const int scol = ((seg ^ (rbase & 7)) << 3);      // pre-swizzled source col (elements)
    const unsigned short* aSrc[4];
    const unsigned short* bSrc[4];
    #pragma unroll
    for (int i = 0; i < 4; ++i) {
        int r = i * 32 + rbase;                       // r&7 == rbase&7
        int ar = idx ? idx[mBase + r] : (mBase + r);
        aSrc[i] = A + (size_t)ar * 512 + scol;
        bSrc[i] = Bt + (size_t)(nBase + r) * 512 + scol;
    }
    const int ldsOfs = (tid & 192) * 8;               // wave-uniform elem base

    f32x4 acc[4][4] = {};

    for (int k0 = 0; k0 < 512; k0 += 64) {
        #pragma unroll
        for (int i = 0; i < 4; ++i) {
            __builtin_amdgcn_global_load_lds(GLOBAL_AS(aSrc[i] + k0), LDS_AS(As + i * 2048 + ldsOfs), 16, 0, 0);
            __builtin_amdgcn_global_load_lds(GLOBAL_AS(bSrc[i] + k0), LDS_AS(Bs + i * 2048 + ldsOfs), 16, 0, 0);
        }
        __syncthreads();
        bf16x8 af[4][2], bfr[4][2];
        #pragma unroll
        for (int mt = 0; mt < 4; ++mt) {
            int row = wm + mt * 16 + lm;
            int sw = row & 7;
            #pragma unroll
            for (int hh = 0; hh < 2; ++hh)
                af[mt][hh] = *(const bf16x8*)(As + row * 64 + (((hh * 4 + lq) ^ sw) << 3));
        }
        #pragma unroll
        for (int nt = 0; nt < 4; ++nt) {
            int row = wn + nt * 16 + lm;
            int sw = row & 7;
            #pragma unroll
            for (int hh = 0; hh < 2; ++hh)
                bfr[nt][hh] = *(const bf16x8*)(Bs + row * 64 + (((hh * 4 + lq) ^ sw) << 3));
        }
        #pragma unroll
        for (int mt = 0; mt < 4; ++mt)
            #pragma unroll
            for (int nt = 0; nt < 4; ++nt) {
                acc[mt][nt] = __builtin_amdgcn_mfma_f32_16x16x32_bf16(af[mt][0], bfr[nt][0], acc[mt][nt], 0, 0, 0);
                acc[mt][nt] = __builtin_amdgcn_mfma_f32_16x16x32_bf16(af[mt][1], bfr[nt][1], acc[mt][nt], 0, 0, 0);
            }
        __syncthreads();
    }
    #pragma unroll
    for (int mt = 0; mt < 4; ++mt)
        #pragma unroll
        for (int nt = 0; nt < 4; ++nt)
            #pragma unroll
            for (int r = 0; r < 4; ++r) {
                int m = mBase + wm + mt * 16 + lq * 4 + r;
                int n = nBase + wn + nt * 16 + lm;
                C[(size_t)m * 512 + n] = f2bf(acc[mt][nt][r]);
            }
}

// ---------------------------------------------------------------- fused score+gate+softmax pass
// Block: 128 t x 32 g. Wave w owns t in [t0+w*32, +32), all 32 g. 2x2 MFMA tiles of 16x16.
// VALU diet: gate weights pre-scaled by 0.125*log2(e) so v_exp_f32 (=2^x) applies directly;
// no max-sub (softmax shift-invariant, |gl|<~6 here so exp is fp32-safe); v_rcp_f32 instead
// of precise divide; alpha2 = 1 - alpha0 - alpha1 (drops one accumulator array -> -16 VGPR);
// single-instruction bf16 converts. __launch_bounds__(256,4) pins 4 waves/SIMD.
__global__ __launch_bounds__(256, 4) void score_pass(const unsigned short* __restrict__ Qp,   // [3][512][512] bf16
                                                     const unsigned short* __restrict__ Kp,   // [3][16384][512] bf16
                                                     const float* __restrict__ gw,            // [8][3][3]
                                                     const float* __restrict__ gb,            // [8][3]
                                                     unsigned short* __restrict__ p_out,      // [8][512][16384] bf16
                                                     float* __restrict__ l_out,               // [8][512]
                                                     float* __restrict__ u_mean,              // [512][16384]
                                                     float* __restrict__ alpha_mean)          // [512][16384][3]
{
    const int tid = threadIdx.x;
    const int lane = tid & 63;
    const int w = tid >> 6;
    const int tw = blockIdx.y * 128 + w * 32;
    const int g0 = blockIdx.x * 32;
    const int lm = lane & 15, lq = lane >> 4;

    float u_sum[2][2][4] = {};      // [mt][nt][r]
    float a0_sum[2][2][4] = {};
    float a1_sum[2][2][4] = {};

    #pragma unroll 1
    for (int h = 0; h < 8; ++h) {
        // gate weights folded with score scale (1/8) and log2(e) for native v_exp_f32
        float W2[3][3], B2[3];
        #pragma unroll
        for (int e = 0; e < 3; ++e)
            #pragma unroll
            for (int f = 0; f < 3; ++f) W2[e][f] = gw[(h * 3 + e) * 3 + f] * (0.125f * L2E);
        #pragma unroll
        for (int f = 0; f < 3; ++f) B2[f] = gb[h * 3 + f] * L2E;

        f32x4 s[3][2][2];
        #pragma unroll
        for (int e = 0; e < 3; ++e) {
            const unsigned short* qbase = Qp + (size_t)e * 512 * 512 + (size_t)(tw + lm) * 512 + h * 64 + lq * 8;
            const unsigned short* kbase = Kp + (size_t)e * N_GENE * 512 + (size_t)(g0 + lm) * 512 + h * 64 + lq * 8;
            bf16x8 q[2][2], k[2][2];
            #pragma unroll
            for (int mt = 0; mt < 2; ++mt) {
                q[mt][0] = *(const bf16x8*)(qbase + mt * 16 * 512);
                q[mt][1] = *(const bf16x8*)(qbase + mt * 16 * 512 + 32);
            }
            #pragma unroll
            for (int nt = 0; nt < 2; ++nt) {
                k[nt][0] = *(const bf16x8*)(kbase + nt * 16 * 512);
                k[nt][1] = *(const bf16x8*)(kbase + nt * 16 * 512 + 32);
            }
            #pragma unroll
            for (int mt = 0; mt < 2; ++mt)
                #pragma unroll
                for (int nt = 0; nt < 2; ++nt) {
                    f32x4 a = {};
                    a = __builtin_amdgcn_mfma_f32_16x16x32_bf16(q[mt][0], k[nt][0], a, 0, 0, 0);
                    a = __builtin_amdgcn_mfma_f32_16x16x32_bf16(q[mt][1], k[nt][1], a, 0, 0, 0);
                    s[e][mt][nt] = a;
                }
        }
        float lpart[2][4] = {};
        #pragma unroll
        for (int mt = 0; mt < 2; ++mt)
            #pragma unroll
            for (int nt = 0; nt < 2; ++nt) {
                unsigned short* pb = p_out + ((size_t)h * N_TF + (tw + mt * 16 + lq * 4)) * N_GENE + (g0 + nt * 16 + lm);
                #pragma unroll
                for (int r = 0; r < 4; ++r) {
                    float s0 = s[0][mt][nt][r];
                    float s1 = s[1][mt][nt][r];
                    float s2 = s[2][mt][nt][r];
                    // gate logits already in log2 domain
                    float gl0 = fmaf(s2, W2[2][0], fmaf(s1, W2[1][0], fmaf(s0, W2[0][0], B2[0])));
                    float gl1 = fmaf(s2, W2[2][1], fmaf(s1, W2[1][1], fmaf(s0, W2[0][1], B2[1])));
                    float gl2 = fmaf(s2, W2[2][2], fmaf(s1, W2[1][2], fmaf(s0, W2[0][2], B2[2])));
                    float e0 = fast_exp2(gl0), e1 = fast_exp2(gl1), e2 = fast_exp2(gl2);
                    float rz = fast_rcp(e0 + e1 + e2);
                    float a0 = e0 * rz, a1 = e1 * rz;
                    float dot = fmaf(e0, s0, fmaf(e1, s1, e2 * s2));
                    float u = dot * (rz * 0.125f);           // = sum_e alpha_e * (s_e/8)
                    float pv = fast_exp2(u * L2E);           // exp(u); |u| small -> safe
                    u_sum[mt][nt][r] += u;
                    a0_sum[mt][nt][r] += a0;
                    a1_sum[mt][nt][r] += a1;
                    lpart[mt][r] += pv;
                    pb[(size_t)r * N_GENE] = f2bf(pv);
                }
            }
        #pragma unroll
        for (int mt = 0; mt < 2; ++mt)
            #pragma unroll
            for (int r = 0; r < 4; ++r) {
                float v = lpart[mt][r];
                v += __shfl_xor(v, 1);
                v += __shfl_xor(v, 2);
                v += __shfl_xor(v, 4);
                v += __shfl_xor(v, 8);
                if (lm == 0) atomicAdd(&l_out[h * N_TF + tw + mt * 16 + lq * 4 + r], v);
            }
    }
    #pragma unroll
    for (int mt = 0; mt < 2; ++mt)
        #pragma unroll
        for (int nt = 0; nt < 2; ++nt)
            #pragma unroll
            for (int r = 0; r < 4; ++r) {
                int t = tw + mt * 16 + lq * 4 + r;
                int g = g0 + nt * 16 + lm;
                u_mean[(size_t)t * N_GENE + g] = u_sum[mt][nt][r] * 0.125f;
                float a0m = a0_sum[mt][nt][r] * 0.125f;
                float a1m = a1_sum[mt][nt][r] * 0.125f;
                size_t base = ((size_t)t * N_GENE + g) * 3;
                alpha_mean[base + 0] = a0m;
                alpha_mean[base + 1] = a1m;
                alpha_mean[base + 2] = 1.0f - a0m - a1m;     // exact: per-h alphas sum to 1
            }
}

// ---------------------------------------------------------------- A_mean finalize (fp32 out)
__global__ __launch_bounds__(256) void finalize_A(const unsigned short* __restrict__ p,
                                                  const float* __restrict__ l,
                                                  float* __restrict__ A_mean) {
    const int t = blockIdx.x;
    float rinv[8];
    #pragma unroll
    for (int h = 0; h < 8; ++h) rinv[h] = 0.125f / l[h * N_TF + t];
    for (int g4 = threadIdx.x * 4; g4 < N_GENE; g4 += 256 * 4) {
        float s0 = 0.f, s1 = 0.f, s2 = 0.f, s3 = 0.f;
        #pragma unroll
        for (int h = 0; h < 8; ++h) {
            ushort4 pv = *(const ushort4*)(p + ((size_t)h * N_TF + t) * N_GENE + g4);
            float r = rinv[h];
            s0 += bf2f(pv.x) * r; s1 += bf2f(pv.y) * r; s2 += bf2f(pv.z) * r; s3 += bf2f(pv.w) * r;
        }
        float4 o; o.x = s0; o.y = s1; o.z = s2; o.w = s3;
        *(float4*)(A_mean + (size_t)t * N_GENE + g4) = o;
    }
}

// ---------------------------------------------------------------- launch
extern "C" void kernel_launch(void* const* d_in, const int* in_sizes, int n_in,
                              void* d_out, int out_size, void* d_ws, size_t ws_size,
                              hipStream_t stream) {
    const float* H_TF  = (const float*)d_in[0];
    const float* H_G   = (const float*)d_in[1];
    // evidence order: e0=bind(seq), e1=coexpr(exp), e2=know(txt)
    const float* z[3]  = { (const float*)d_in[3], (const float*)d_in[2], (const float*)d_in[4] };
    const int* tf_idx  = (const int*)d_in[5];
    const float* Wq[3] = { (const float*)d_in[6], (const float*)d_in[8], (const float*)d_in[10] };
    const float* Wk[3] = { (const float*)d_in[7], (const float*)d_in[9], (const float*)d_in[11] };
    const float* gw    = (const float*)d_in[12];
    const float* gb    = (const float*)d_in[13];
    float* out = (float*)d_out;

    // d_out layout (fp32): H_TF | H_G | A_mean | u_mean | alpha_mean
    float* out_HTF   = out;
    float* out_HG    = out + 262144;
    float* out_Amean = out + 262144 + 8388608;
    float* out_umean = out + 262144 + 8388608 + 8388608;
    float* out_alpha = out + 262144 + 8388608 + 8388608 + 8388608;

    // ws layout (bf16 intermediates)
    unsigned short* Wt = (unsigned short*)d_ws;        // 6 * 262144  (slot e*2 = Wq_e^T, e*2+1 = Wk_e^T)
    unsigned short* Kp = Wt + 6 * 262144;              // 3 * 16384*512
    unsigned short* Qp = Kp + 3 * (size_t)N_GENE * 512;// 3 * 512*512
    unsigned short* Pp = Qp + 3 * 512 * 512;           // 8 * 512 * 16384
    float*          Lp = (float*)(Pp + (size_t)8 * N_TF * N_GENE);  // 8*512 floats
    // zb (bf16 copies of z) aliases Pp: zb is dead before score_pass writes Pp
    unsigned short* Zb = Pp;                           // 3 * 16384*512 <= Pp size

    zerof<<<16, 256, 0, stream>>>(Lp, 8 * N_TF);

    transpose6<<<dim3(16, 16, 6), dim3(32, 8), 0, stream>>>(
        Wq[0], Wk[0], Wq[1], Wk[1], Wq[2], Wk[2], Wt);

    cvt3<<<dim3(N_GENE * 512 / (256 * 8), 1, 3), 256, 0, stream>>>(z[0], z[1], z[2], Zb);

    for (int e = 0; e < 3; ++e) {
        const unsigned short* zb = Zb + (size_t)e * N_GENE * 512;
        // K projection: [16384,512] = z_e @ Wk_e
        gemm_bf16<<<dim3(4, 128), 256, 0, stream>>>(zb, Wt + (size_t)(e * 2 + 1) * 262144,
                                                    Kp + (size_t)e * N_GENE * 512, nullptr);
        // Q projection: [512,512] = z_e[tf_idx] @ Wq_e
        gemm_bf16<<<dim3(4, 4), 256, 0, stream>>>(zb, Wt + (size_t)(e * 2) * 262144,
                                                  Qp + (size_t)e * 512 * 512, tf_idx);
    }

    score_pass<<<dim3(N_GENE / 32, N_TF / 128), 256, 0, stream>>>(
        Qp, Kp, gw, gb, Pp, Lp, out_umean, out_alpha);

    finalize_A<<<N_TF, 256, 0, stream>>>(Pp, Lp, out_Amean);

    copy16<<<(262144 * 4 / 16 + 255) / 256, 256, 0, stream>>>((const int4*)H_TF, (int4*)out_HTF, 262144 * 4 / 16);
    copy16<<<(8388608 * 4 / 16 + 255) / 256, 256, 0, stream>>>((const int4*)H_G, (int4*)out_HG, 8388608 * 4 / 16);
}

// Round 3
// 674.357 us; speedup vs baseline: 1.1866x; 1.1669x over previous
//
#include <hip/hip_runtime.h>
#include <hip/hip_bf16.h>
#include <stdint.h>

typedef __attribute__((ext_vector_type(4))) float f32x4;
typedef __attribute__((ext_vector_type(8))) short bf16x8;
typedef __attribute__((ext_vector_type(8))) unsigned short u16x8;

#define N_GENE 16384
#define N_TF   512
#define DMODEL 512
#define L2E    1.44269504088896340736f

__device__ __forceinline__ float bf2f(unsigned short u) {
    union { unsigned int i; float f; } v; v.i = ((unsigned int)u) << 16; return v.f;
}
// single-instruction RNE f32->bf16
__device__ __forceinline__ unsigned short f2bf(float f) {
    unsigned int r;
    asm("v_cvt_pk_bf16_f32 %0, %1, %1" : "=v"(r) : "v"(f));
    return (unsigned short)r;
}
__device__ __forceinline__ float fast_rcp(float x) {
    float r; asm("v_rcp_f32 %0, %1" : "=v"(r) : "v"(x)); return r;
}
__device__ __forceinline__ float fast_exp2(float x) {
    float r; asm("v_exp_f32 %0, %1" : "=v"(r) : "v"(x)); return r;
}

#define GLOBAL_AS(p) ((const __attribute__((address_space(1))) void*)(p))
#define LDS_AS(p)    ((__attribute__((address_space(3))) void*)(p))

// ---------------------------------------------------------------- prep: zerof + transpose6 + cvt3 fused
// blocks [0,12288): fp32->bf16 convert of z0/z1/z2 into Zb (4096 blocks each)
// blocks [12288,13824): transpose+convert 6 weight matrices (256 blocks each)
// block 13824: zero Lp (8*512 floats)
__global__ __launch_bounds__(256) void prep(const float* __restrict__ z0, const float* __restrict__ z1,
                                            const float* __restrict__ z2, unsigned short* __restrict__ zb,
                                            const float* __restrict__ w0, const float* __restrict__ w1,
                                            const float* __restrict__ w2, const float* __restrict__ w3,
                                            const float* __restrict__ w4, const float* __restrict__ w5,
                                            unsigned short* __restrict__ wt, float* __restrict__ lp) {
    __shared__ unsigned short tile[32][33];
    const int b = blockIdx.x;
    const int tid = threadIdx.x;
    if (b < 12288) {
        const float* s = b < 4096 ? z0 : (b < 8192 ? z1 : z2);
        const int m = b >> 12;
        const int blk = b & 4095;
        size_t i = ((size_t)blk * 256 + tid) * 8;
        float4 a = *(const float4*)(s + i);
        float4 c = *(const float4*)(s + i + 4);
        unsigned int q0, q1, q2, q3;
        asm("v_cvt_pk_bf16_f32 %0, %1, %2" : "=v"(q0) : "v"(a.x), "v"(a.y));
        asm("v_cvt_pk_bf16_f32 %0, %1, %2" : "=v"(q1) : "v"(a.z), "v"(a.w));
        asm("v_cvt_pk_bf16_f32 %0, %1, %2" : "=v"(q2) : "v"(c.x), "v"(c.y));
        asm("v_cvt_pk_bf16_f32 %0, %1, %2" : "=v"(q3) : "v"(c.z), "v"(c.w));
        uint4 o; o.x = q0; o.y = q1; o.z = q2; o.w = q3;
        *(uint4*)(zb + (size_t)m * (size_t)N_GENE * 512 + i) = o;
    } else if (b < 13824) {
        const float* srcs[6] = { w0, w1, w2, w3, w4, w5 };
        const int b2 = b - 12288;
        const int m = b2 >> 8;
        const int rem = b2 & 255;
        const int by = rem >> 4, bx = rem & 15;
        const int tx = tid & 31, ty8 = tid >> 5;
        const float* src = srcs[m];
        const int x = bx * 32 + tx;
        const int y0 = by * 32;
        for (int i = ty8; i < 32; i += 8)
            tile[i][tx] = f2bf(src[(size_t)(y0 + i) * 512 + x]);
        __syncthreads();
        const int xo = by * 32 + tx;
        const int yo0 = bx * 32;
        unsigned short* d = wt + (size_t)m * 512 * 512;
        for (int i = ty8; i < 32; i += 8)
            d[(size_t)(yo0 + i) * 512 + xo] = tile[tx][i];
    } else {
        for (int i = tid; i < 8 * N_TF; i += 256) lp[i] = 0.f;
    }
}

// ---------------------------------------------------------------- GEMM C[M,512] = A[M,512] @ Bt^T
// All 6 projections in one dispatch: grid (4, 132, 3); y<128 -> K-proj tile, y>=128 -> Q-proj (gathered).
// Tile 128x128, BK=64, 4 waves (2x2), mfma 16x16x32; global_load_lds width=16 with both-sides XOR swizzle.
__global__ __launch_bounds__(256) void gemm_all(const unsigned short* __restrict__ Zb,
                                                const unsigned short* __restrict__ Wt,
                                                unsigned short* __restrict__ Kp,
                                                unsigned short* __restrict__ Qp,
                                                const int* __restrict__ tf_idx) {
    __shared__ unsigned short As[128 * 64];   // 16 KB
    __shared__ unsigned short Bs[128 * 64];   // 16 KB
    const int e = blockIdx.z;
    const unsigned short* A = Zb + (size_t)e * N_GENE * 512;
    const unsigned short* Bt;
    unsigned short* C;
    const int* idx;
    int mBase;
    if (blockIdx.y < 128) {
        Bt = Wt + (size_t)(e * 2 + 1) * 262144;
        C = Kp + (size_t)e * N_GENE * 512;
        idx = nullptr;
        mBase = blockIdx.y * 128;
    } else {
        Bt = Wt + (size_t)(e * 2) * 262144;
        C = Qp + (size_t)e * 512 * 512;
        idx = tf_idx;
        mBase = (blockIdx.y - 128) * 128;
    }
    const int tid = threadIdx.x;
    const int lane = tid & 63;
    const int w = tid >> 6;
    const int nBase = blockIdx.x * 128;
    const int wm = (w & 1) * 64;
    const int wn = (w >> 1) * 64;
    const int lm = lane & 15, lq = lane >> 4;

    const int rbase = tid >> 3;                       // 0..31
    const int seg = tid & 7;
    const int scol = ((seg ^ (rbase & 7)) << 3);      // pre-swizzled source col (elements)
    const unsigned short* aSrc[4];
    const unsigned short* bSrc[4];
    #pragma unroll
    for (int i = 0; i < 4; ++i) {
        int r = i * 32 + rbase;
        int ar = idx ? idx[mBase + r] : (mBase + r);
        aSrc[i] = A + (size_t)ar * 512 + scol;
        bSrc[i] = Bt + (size_t)(nBase + r) * 512 + scol;
    }
    const int ldsOfs = (tid & 192) * 8;               // wave-uniform elem base

    f32x4 acc[4][4] = {};

    for (int k0 = 0; k0 < 512; k0 += 64) {
        #pragma unroll
        for (int i = 0; i < 4; ++i) {
            __builtin_amdgcn_global_load_lds(GLOBAL_AS(aSrc[i] + k0), LDS_AS(As + i * 2048 + ldsOfs), 16, 0, 0);
            __builtin_amdgcn_global_load_lds(GLOBAL_AS(bSrc[i] + k0), LDS_AS(Bs + i * 2048 + ldsOfs), 16, 0, 0);
        }
        __syncthreads();
        bf16x8 af[4][2], bfr[4][2];
        #pragma unroll
        for (int mt = 0; mt < 4; ++mt) {
            int row = wm + mt * 16 + lm;
            int sw = row & 7;
            #pragma unroll
            for (int hh = 0; hh < 2; ++hh)
                af[mt][hh] = *(const bf16x8*)(As + row * 64 + (((hh * 4 + lq) ^ sw) << 3));
        }
        #pragma unroll
        for (int nt = 0; nt < 4; ++nt) {
            int row = wn + nt * 16 + lm;
            int sw = row & 7;
            #pragma unroll
            for (int hh = 0; hh < 2; ++hh)
                bfr[nt][hh] = *(const bf16x8*)(Bs + row * 64 + (((hh * 4 + lq) ^ sw) << 3));
        }
        #pragma unroll
        for (int mt = 0; mt < 4; ++mt)
            #pragma unroll
            for (int nt = 0; nt < 4; ++nt) {
                acc[mt][nt] = __builtin_amdgcn_mfma_f32_16x16x32_bf16(af[mt][0], bfr[nt][0], acc[mt][nt], 0, 0, 0);
                acc[mt][nt] = __builtin_amdgcn_mfma_f32_16x16x32_bf16(af[mt][1], bfr[nt][1], acc[mt][nt], 0, 0, 0);
            }
        __syncthreads();
    }
    #pragma unroll
    for (int mt = 0; mt < 4; ++mt)
        #pragma unroll
        for (int nt = 0; nt < 4; ++nt)
            #pragma unroll
            for (int r = 0; r < 4; ++r) {
                int m = mBase + wm + mt * 16 + lq * 4 + r;
                int n = nBase + wn + nt * 16 + lm;
                C[(size_t)m * 512 + n] = f2bf(acc[mt][nt][r]);
            }
}

// ---------------------------------------------------------------- fused score+gate+softmax pass
// Block: 64 t x 64 g (full-128B-line outputs). 4 waves: wave w owns t in [tw,+32), g in [g0,+32).
// XCD-chunked swizzle, ty-innermost: the 8 t-blocks sharing the same 64 K-rows run back-to-back
// on the same XCD -> K read once into L2 per XCD. Streaming outputs use nontemporal stores
// (no L2 write-allocate). Gate math pre-scaled into log2 domain; rcp/exp2 fast paths.
__global__ __launch_bounds__(256, 4) void score_pass(const unsigned short* __restrict__ Qp,   // [3][512][512] bf16
                                                     const unsigned short* __restrict__ Kp,   // [3][16384][512] bf16
                                                     const float* __restrict__ gw,            // [8][3][3]
                                                     const float* __restrict__ gb,            // [8][3]
                                                     unsigned short* __restrict__ p_out,      // [8][512][16384] bf16
                                                     float* __restrict__ l_out,               // [8][512]
                                                     float* __restrict__ u_mean,              // [512][16384]
                                                     float* __restrict__ alpha_mean)          // [512][16384][3]
{
    const int tid = threadIdx.x;
    const int lane = tid & 63;
    const int w = tid >> 6;
    // chunked XCD swizzle: bid%8 = XCD; each XCD gets contiguous work range o in [c*256, c*256+256)
    const int bid = blockIdx.x;                 // grid = 2048 (1-D)
    const int o = (bid & 7) * 256 + (bid >> 3);
    const int gx = o >> 3;                      // 0..255 : 64-gene chunk
    const int ty = o & 7;                       // 0..7   : 64-tf chunk (innermost -> K reuse in L2)
    const int tw = ty * 64 + (w & 1) * 32;
    const int g0 = gx * 64 + (w >> 1) * 32;
    const int lm = lane & 15, lq = lane >> 4;

    float u_sum[2][2][4] = {};      // [mt][nt][r]
    float a0_sum[2][2][4] = {};
    float a1_sum[2][2][4] = {};

    #pragma unroll 1
    for (int h = 0; h < 8; ++h) {
        // gate weights folded with score scale (1/8) and log2(e) for native v_exp_f32
        float W2[3][3], B2[3];
        #pragma unroll
        for (int e = 0; e < 3; ++e)
            #pragma unroll
            for (int f = 0; f < 3; ++f) W2[e][f] = gw[(h * 3 + e) * 3 + f] * (0.125f * L2E);
        #pragma unroll
        for (int f = 0; f < 3; ++f) B2[f] = gb[h * 3 + f] * L2E;

        f32x4 s[3][2][2];
        #pragma unroll
        for (int e = 0; e < 3; ++e) {
            const unsigned short* qbase = Qp + (size_t)e * 512 * 512 + (size_t)(tw + lm) * 512 + h * 64 + lq * 8;
            const unsigned short* kbase = Kp + (size_t)e * N_GENE * 512 + (size_t)(g0 + lm) * 512 + h * 64 + lq * 8;
            bf16x8 q[2][2], k[2][2];
            #pragma unroll
            for (int mt = 0; mt < 2; ++mt) {
                q[mt][0] = *(const bf16x8*)(qbase + mt * 16 * 512);
                q[mt][1] = *(const bf16x8*)(qbase + mt * 16 * 512 + 32);
            }
            #pragma unroll
            for (int nt = 0; nt < 2; ++nt) {
                k[nt][0] = *(const bf16x8*)(kbase + nt * 16 * 512);
                k[nt][1] = *(const bf16x8*)(kbase + nt * 16 * 512 + 32);
            }
            #pragma unroll
            for (int mt = 0; mt < 2; ++mt)
                #pragma unroll
                for (int nt = 0; nt < 2; ++nt) {
                    f32x4 a = {};
                    a = __builtin_amdgcn_mfma_f32_16x16x32_bf16(q[mt][0], k[nt][0], a, 0, 0, 0);
                    a = __builtin_amdgcn_mfma_f32_16x16x32_bf16(q[mt][1], k[nt][1], a, 0, 0, 0);
                    s[e][mt][nt] = a;
                }
        }
        float lpart[2][4] = {};
        #pragma unroll
        for (int mt = 0; mt < 2; ++mt)
            #pragma unroll
            for (int nt = 0; nt < 2; ++nt) {
                unsigned short* pb = p_out + ((size_t)h * N_TF + (tw + mt * 16 + lq * 4)) * N_GENE + (g0 + nt * 16 + lm);
                #pragma unroll
                for (int r = 0; r < 4; ++r) {
                    float s0 = s[0][mt][nt][r];
                    float s1 = s[1][mt][nt][r];
                    float s2 = s[2][mt][nt][r];
                    float gl0 = fmaf(s2, W2[2][0], fmaf(s1, W2[1][0], fmaf(s0, W2[0][0], B2[0])));
                    float gl1 = fmaf(s2, W2[2][1], fmaf(s1, W2[1][1], fmaf(s0, W2[0][1], B2[1])));
                    float gl2 = fmaf(s2, W2[2][2], fmaf(s1, W2[1][2], fmaf(s0, W2[0][2], B2[2])));
                    float e0 = fast_exp2(gl0), e1 = fast_exp2(gl1), e2 = fast_exp2(gl2);
                    float rz = fast_rcp(e0 + e1 + e2);
                    float a0 = e0 * rz, a1 = e1 * rz;
                    float dot = fmaf(e0, s0, fmaf(e1, s1, e2 * s2));
                    float u = dot * (rz * 0.125f);           // = sum_e alpha_e * (s_e/8)
                    float pv = fast_exp2(u * L2E);           // exp(u); |u| small -> fp32-safe
                    u_sum[mt][nt][r] += u;
                    a0_sum[mt][nt][r] += a0;
                    a1_sum[mt][nt][r] += a1;
                    lpart[mt][r] += pv;
                    __builtin_nontemporal_store(f2bf(pv), pb + (size_t)r * N_GENE);
                }
            }
        #pragma unroll
        for (int mt = 0; mt < 2; ++mt)
            #pragma unroll
            for (int r = 0; r < 4; ++r) {
                float v = lpart[mt][r];
                v += __shfl_xor(v, 1);
                v += __shfl_xor(v, 2);
                v += __shfl_xor(v, 4);
                v += __shfl_xor(v, 8);
                if (lm == 0) atomicAdd(&l_out[h * N_TF + tw + mt * 16 + lq * 4 + r], v);
            }
    }
    #pragma unroll
    for (int mt = 0; mt < 2; ++mt)
        #pragma unroll
        for (int nt = 0; nt < 2; ++nt)
            #pragma unroll
            for (int r = 0; r < 4; ++r) {
                int t = tw + mt * 16 + lq * 4 + r;
                int g = g0 + nt * 16 + lm;
                __builtin_nontemporal_store(u_sum[mt][nt][r] * 0.125f, u_mean + (size_t)t * N_GENE + g);
                float a0m = a0_sum[mt][nt][r] * 0.125f;
                float a1m = a1_sum[mt][nt][r] * 0.125f;
                size_t base = ((size_t)t * N_GENE + g) * 3;
                __builtin_nontemporal_store(a0m, alpha_mean + base + 0);
                __builtin_nontemporal_store(a1m, alpha_mean + base + 1);
                __builtin_nontemporal_store(1.0f - a0m - a1m, alpha_mean + base + 2);
            }
}

// ---------------------------------------------------------------- A_mean finalize (fp32 out)
// grid (512, 4): block = (t, quarter of genes). 16B nt loads of P, nt stores of A (ext-vector f32x4).
__global__ __launch_bounds__(256) void finalize_A(const unsigned short* __restrict__ p,
                                                  const float* __restrict__ l,
                                                  float* __restrict__ A_mean) {
    const int t = blockIdx.x;
    float rinv[8];
    #pragma unroll
    for (int h = 0; h < 8; ++h) rinv[h] = 0.125f / l[h * N_TF + t];
    const int gbase = blockIdx.y * 4096 + threadIdx.x * 8;
    #pragma unroll
    for (int gg = 0; gg < 2; ++gg) {
        int g8 = gbase + gg * 2048;
        float s[8] = {};
        #pragma unroll
        for (int h = 0; h < 8; ++h) {
            u16x8 pv = __builtin_nontemporal_load((const u16x8*)(p + ((size_t)h * N_TF + t) * N_GENE + g8));
            float r = rinv[h];
            #pragma unroll
            for (int j = 0; j < 8; ++j) s[j] += bf2f(pv[j]) * r;
        }
        f32x4 o0, o1;
        o0[0] = s[0]; o0[1] = s[1]; o0[2] = s[2]; o0[3] = s[3];
        o1[0] = s[4]; o1[1] = s[5]; o1[2] = s[6]; o1[3] = s[7];
        __builtin_nontemporal_store(o0, (f32x4*)(A_mean + (size_t)t * N_GENE + g8));
        __builtin_nontemporal_store(o1, (f32x4*)(A_mean + (size_t)t * N_GENE + g8 + 4));
    }
}

// ---------------------------------------------------------------- H_TF + H_G passthrough in one launch
__global__ __launch_bounds__(256) void copy_all(const int4* __restrict__ a, const int4* __restrict__ b,
                                                int4* __restrict__ da, int4* __restrict__ db) {
    const int bx = blockIdx.x;
    if (bx < 256) {
        int i = bx * 256 + threadIdx.x;            // 65536 int4 = 1 MB H_TF
        da[i] = a[i];
    } else {
        int i = (bx - 256) * 256 + threadIdx.x;    // 2097152 int4 = 32 MB H_G
        db[i] = b[i];
    }
}

// ---------------------------------------------------------------- launch
extern "C" void kernel_launch(void* const* d_in, const int* in_sizes, int n_in,
                              void* d_out, int out_size, void* d_ws, size_t ws_size,
                              hipStream_t stream) {
    const float* H_TF  = (const float*)d_in[0];
    const float* H_G   = (const float*)d_in[1];
    // evidence order: e0=bind(seq), e1=coexpr(exp), e2=know(txt)
    const float* z[3]  = { (const float*)d_in[3], (const float*)d_in[2], (const float*)d_in[4] };
    const int* tf_idx  = (const int*)d_in[5];
    const float* Wq[3] = { (const float*)d_in[6], (const float*)d_in[8], (const float*)d_in[10] };
    const float* Wk[3] = { (const float*)d_in[7], (const float*)d_in[9], (const float*)d_in[11] };
    const float* gw    = (const float*)d_in[12];
    const float* gb    = (const float*)d_in[13];
    float* out = (float*)d_out;

    // d_out layout (fp32): H_TF | H_G | A_mean | u_mean | alpha_mean
    float* out_HTF   = out;
    float* out_HG    = out + 262144;
    float* out_Amean = out + 262144 + 8388608;
    float* out_umean = out + 262144 + 8388608 + 8388608;
    float* out_alpha = out + 262144 + 8388608 + 8388608 + 8388608;

    // ws layout (bf16 intermediates)
    unsigned short* Wt = (unsigned short*)d_ws;        // 6 * 262144  (slot e*2 = Wq_e^T, e*2+1 = Wk_e^T)
    unsigned short* Kp = Wt + 6 * 262144;              // 3 * 16384*512
    unsigned short* Qp = Kp + 3 * (size_t)N_GENE * 512;// 3 * 512*512
    unsigned short* Pp = Qp + 3 * 512 * 512;           // 8 * 512 * 16384
    float*          Lp = (float*)(Pp + (size_t)8 * N_TF * N_GENE);  // 8*512 floats
    // Zb (bf16 copies of z) aliases Pp: Zb is dead before score_pass writes Pp
    unsigned short* Zb = Pp;                           // 3 * 16384*512 <= Pp size

    // 1) all preprocessing in one dispatch
    prep<<<13825, 256, 0, stream>>>(z[0], z[1], z[2], Zb,
                                    Wq[0], Wk[0], Wq[1], Wk[1], Wq[2], Wk[2], Wt, Lp);

    // 2) all 6 projection GEMMs in one dispatch
    gemm_all<<<dim3(4, 132, 3), 256, 0, stream>>>(Zb, Wt, Kp, Qp, tf_idx);

    // 3) fused score+gate+softmax
    score_pass<<<2048, 256, 0, stream>>>(Qp, Kp, gw, gb, Pp, Lp, out_umean, out_alpha);

    // 4) A_mean normalize+mean
    finalize_A<<<dim3(512, 4), 256, 0, stream>>>(Pp, Lp, out_Amean);

    // 5) passthrough copies
    copy_all<<<256 + 8192, 256, 0, stream>>>((const int4*)H_TF, (const int4*)H_G,
                                             (int4*)out_HTF, (int4*)out_HG);
}